// Round 1
// baseline (643.200 us; speedup 1.0000x reference)
//
#include <hip/hip_runtime.h>
#include <math.h>

// Problem constants (fixed by the reference): B=8, C=D=512, H=W=128
#define BB   8
#define CC   512
#define DD   512
#define HW   16384
#define HW4  4096    // HW / 4 (float4 count per (b,c) row)
#define NCHUNK 64    // hw-chunks per batch; chunk = 64 float4 = 256 positions

// Algebraic restructuring (query length == 1):
//   logits = (q@Wk)·x  (+ q·bk, dropped: softmax shift-invariant)
//   gate   = Wv·(attn-pooled x) + bv   (since sum(attn)==1)
// plus ONLINE SOFTMAX fusion: logits+softmax+pool collapse into ONE pass
// over x (per-chunk local max/sum + partial pooled, merged by k_combine).
// => x is read twice (fused + out) and out written once ≈ 0.8 GB HBM
//    (phase-3 re-read of the fused kernel hits L2-tail/L3), vs 1.07 GB before.

// ---- A: q[b,c] = context[b,:]·Wq[c,:] + bq[c]   (tiny) ----
__global__ __launch_bounds__(256) void k_qproj(const float* __restrict__ ctx,
                                               const float* __restrict__ Wq,
                                               const float* __restrict__ bq,
                                               float* __restrict__ q) {
    int t = blockIdx.x * 256 + threadIdx.x;       // 0..4095
    int b = t >> 9, c = t & (CC - 1);
    const float4* cr = (const float4*)(ctx + (size_t)b * DD);
    const float4* wr = (const float4*)(Wq + (size_t)c * DD);
    float acc = 0.f;
    #pragma unroll 8
    for (int d = 0; d < DD / 4; ++d) {
        float4 a = cr[d], w = wr[d];
        acc += a.x * w.x + a.y * w.y + a.z * w.z + a.w * w.w;
    }
    q[t] = acc + bq[c];
}

// ---- B: qk[b,c] = sum_o q[b,o] * Wk[o,c]   (tiny, coalesced over c) ----
__global__ __launch_bounds__(256) void k_qk(const float* __restrict__ q,
                                            const float* __restrict__ Wk,
                                            float* __restrict__ qk) {
    __shared__ float qs[CC];
    int b = blockIdx.x >> 1;                      // 2 blocks per batch
    int c = (blockIdx.x & 1) * 256 + threadIdx.x;
    for (int i = threadIdx.x; i < CC; i += 256) qs[i] = q[b * CC + i];
    __syncthreads();
    float acc = 0.f;
    #pragma unroll 8
    for (int o = 0; o < CC; ++o) acc += qs[o] * Wk[(size_t)o * CC + c];
    qk[b * CC + c] = acc;
}

// ---- C (fused logits + local softmax + partial pool): ONE pass over x ----
// Block = (b, chunk of 256 hw positions). Phase 1: logits for the chunk
// (identical structure to the old k_logits, 64 float4/block). Phase 2:
// wave 0 computes chunk-local max M, p = exp(l-M), s = sum(p); stats to
// global. Phase 3: all 4 waves re-read the SAME 512 KB (L2 tail + L3-hot,
// channels walked in reverse so the recently-read tail hits L2) and
// accumulate part[c] = sum_hw p*x — per-channel 64-lane shuffle reduce
// (~19 VALU per 16B load; VALU stays far below the ceiling at HBM speeds).
__global__ __launch_bounds__(256) void k_fused(const float* __restrict__ x,
                                               const float* __restrict__ qk,
                                               float* __restrict__ part,    // [B*NCHUNK][CC]
                                               float* __restrict__ stats) { // [B*NCHUNK][2]
    __shared__ float  qs[CC];
    __shared__ float4 comb[3][64];
    __shared__ float4 p4s[64];
    __shared__ float  partLDS[CC];
    int b     = blockIdx.x >> 6;                  // NCHUNK = 64 blocks per batch
    int chunk = blockIdx.x & 63;
    int wave = threadIdx.x >> 6, lane = threadIdx.x & 63;
    int hw4 = chunk * 64 + lane;
    for (int i = threadIdx.x; i < CC; i += 256) qs[i] = qk[b * CC + i];
    __syncthreads();
    const float4* x4 = (const float4*)x;
    size_t base = (size_t)b * CC * HW4 + (size_t)(wave * 128) * HW4 + hw4;
    float ax = 0.f, ay = 0.f, az = 0.f, aw = 0.f;
    #pragma unroll 8
    for (int c = 0; c < 128; ++c) {
        float4 v = x4[base + (size_t)c * HW4];
        float w = qs[wave * 128 + c];
        ax += w * v.x; ay += w * v.y; az += w * v.z; aw += w * v.w;
    }
    if (wave > 0) {
        float4 p = { ax, ay, az, aw };
        comb[wave - 1][lane] = p;
    }
    __syncthreads();
    if (wave == 0) {
        #pragma unroll
        for (int w2 = 0; w2 < 3; ++w2) {
            float4 p = comb[w2][lane];
            ax += p.x; ay += p.y; az += p.z; aw += p.w;
        }
        const float scale = 0.04419417382415922f; // 512^-0.5
        ax *= scale; ay *= scale; az *= scale; aw *= scale;
        float m = fmaxf(fmaxf(ax, ay), fmaxf(az, aw));
        #pragma unroll
        for (int off = 32; off; off >>= 1) m = fmaxf(m, __shfl_xor(m, off));
        float4 p;                                  // chunk-local softmax numerators
        p.x = expf(ax - m); p.y = expf(ay - m);
        p.z = expf(az - m); p.w = expf(aw - m);
        float s = p.x + p.y + p.z + p.w;
        #pragma unroll
        for (int off = 32; off; off >>= 1) s += __shfl_xor(s, off);
        p4s[lane] = p;
        if (lane == 0) { stats[blockIdx.x * 2] = m; stats[blockIdx.x * 2 + 1] = s; }
    }
    __syncthreads();
    float4 pv = p4s[lane];                         // per-lane weights, all waves
    #pragma unroll 4
    for (int c = 127; c >= 0; --c) {               // reverse: L2-hot tail first
        float4 v = x4[base + (size_t)c * HW4];
        float r = pv.x * v.x + pv.y * v.y + pv.z * v.z + pv.w * v.w;
        #pragma unroll
        for (int off = 32; off; off >>= 1) r += __shfl_down(r, off);
        if (lane == 0) partLDS[wave * 128 + c] = r;
    }
    __syncthreads();
    float4* pr = (float4*)(part + (size_t)blockIdx.x * CC);
    for (int i = threadIdx.x; i < CC / 4; i += 256) pr[i] = ((float4*)partLDS)[i];
}

// ---- D: merge per-chunk (M, s, part) -> pooled_attn[b,c] (tiny) ----
// pooled[c] = sum_ch e^{M_ch-M} part[ch][c] / (sum_ch e^{M_ch-M} s_ch)
__global__ __launch_bounds__(256) void k_combine(const float* __restrict__ part,
                                                 const float* __restrict__ stats,
                                                 float* __restrict__ pooled) {
    __shared__ float wgt[NCHUNK];
    int b = blockIdx.x, tid = threadIdx.x;
    if (tid < 64) {                                // one full wave -> shfl defined
        float mc = stats[(b * NCHUNK + tid) * 2];
        float sc = stats[(b * NCHUNK + tid) * 2 + 1];
        float m = mc;
        #pragma unroll
        for (int off = 32; off; off >>= 1) m = fmaxf(m, __shfl_xor(m, off));
        float w = expf(mc - m);
        float d = w * sc;
        #pragma unroll
        for (int off = 32; off; off >>= 1) d += __shfl_xor(d, off);
        wgt[tid] = w / d;                          // normalization folded in
    }
    __syncthreads();
    for (int c = tid; c < CC; c += 256) {
        float acc = 0.f;
        #pragma unroll 8
        for (int ch = 0; ch < NCHUNK; ++ch)
            acc += wgt[ch] * part[(size_t)(b * NCHUNK + ch) * CC + c];
        pooled[b * CC + c] = acc;
    }
}

// ---- F: gate[b,o] = Wv[o,:]·pooled[b,:] + bv[o]   (tiny) ----
__global__ __launch_bounds__(256) void k_gate(const float* __restrict__ pooled,
                                              const float* __restrict__ Wv,
                                              const float* __restrict__ bv,
                                              float* __restrict__ gate) {
    int t = blockIdx.x * 256 + threadIdx.x;       // 0..4095
    int b = t >> 9, o = t & (CC - 1);
    const float4* pr = (const float4*)(pooled + (size_t)b * CC);
    const float4* wr = (const float4*)(Wv + (size_t)o * CC);
    float acc = 0.f;
    #pragma unroll 8
    for (int i = 0; i < CC / 4; ++i) {
        float4 p = pr[i], w = wr[i];
        acc += p.x * w.x + p.y * w.y + p.z * w.z + p.w * w.w;
    }
    gate[t] = acc + bv[o];
}

// ---- G: out[b,c,hw] = x[b,c,hw] * gate[b,c]   (read+write: 536 MB) ----
__global__ __launch_bounds__(256) void k_out(const float* __restrict__ x,
                                             const float* __restrict__ gate,
                                             float* __restrict__ out) {
    int bc = blockIdx.x;                          // 0..4095
    float g = gate[bc];
    const float4* xr = (const float4*)x   + (size_t)bc * HW4;
    float4*       orow = (float4*)out     + (size_t)bc * HW4;
    #pragma unroll 8
    for (int i = threadIdx.x; i < HW4; i += 256) {
        float4 v = xr[i];
        float4 o = { v.x * g, v.y * g, v.z * g, v.w * g };
        orow[i] = o;
    }
}

extern "C" void kernel_launch(void* const* d_in, const int* in_sizes, int n_in,
                              void* d_out, int out_size, void* d_ws, size_t ws_size,
                              hipStream_t stream) {
    const float* x   = (const float*)d_in[0];
    const float* ctx = (const float*)d_in[1];
    const float* Wq  = (const float*)d_in[2];
    const float* bq  = (const float*)d_in[3];
    const float* Wk  = (const float*)d_in[4];
    // d_in[5] = bk: per-batch constant in logits -> dropped (softmax shift-invariant)
    const float* Wv  = (const float*)d_in[6];
    const float* bv  = (const float*)d_in[7];
    float* out = (float*)d_out;

    // Workspace layout (floats): everything written before read, no zero-init.
    float* ws     = (float*)d_ws;
    float* q      = ws;                 // 4096
    float* qk     = ws + 4096;          // 4096
    float* pooled = ws + 8192;          // 4096
    float* gate   = ws + 12288;         // 4096
    float* stats  = ws + 16384;         // 1024  (512 chunks x {M, s})
    float* part   = ws + 17408;         // 262144 (512 chunks x 512 channels)

    k_qproj  <<<  16, 256, 0, stream>>>(ctx, Wq, bq, q);
    k_qk     <<<  16, 256, 0, stream>>>(q, Wk, qk);
    k_fused  <<< 512, 256, 0, stream>>>(x, qk, part, stats);
    k_combine<<<  BB, 256, 0, stream>>>(part, stats, pooled);
    k_gate   <<<  16, 256, 0, stream>>>(pooled, Wv, bv, gate);
    k_out    <<<4096, 256, 0, stream>>>(x, gate, out);
}

// Round 2
// 618.891 us; speedup vs baseline: 1.0393x; 1.0393x over previous
//
#include <hip/hip_runtime.h>
#include <math.h>

// Problem constants (fixed by the reference): B=8, C=D=512, H=W=128
#define BB   8
#define CC   512
#define DD   512
#define HW   16384
#define HW4  4096    // HW / 4 (float4 count per (b,c) row)
#define NCHUNK 64    // hw-chunks per batch; chunk = 256 positions = 64 float4

// Algebraic restructuring (query length == 1):
//   logits = (q@Wk)·x  (+ q·bk, dropped: softmax shift-invariant)
//   gate   = Wv·(attn-pooled x) + bv   (since sum(attn)==1)
// Softmax is folded into the pipeline:
//   logits pass emits p = exp(l - M_chunk) + per-chunk (M, s) stats;
//   pool pass applies wgt[ch] = e^{M_ch-M}/D as a wave-uniform scalar.
// => no standalone softmax dispatch (8-block kernel that idled 97% of CUs),
//    5 dispatches total, same 1.07 GB big-pass traffic as the 616 µs best.
// Lesson from last round: the per-channel shuffle-reduce pool (fused phase 3)
// is latency-chain-bound and loses to the per-(b,c)-row contiguous pool.

// ---- A: qk[b,c] = sum_o (ctx[b]·Wq[o] + bq[o]) * Wk[o,c]  (fused, tiny) ----
// 2 blocks per batch; each block computes full q[b,:] into LDS (redundant x2,
// trivial), then 256 coalesced columns of qk.
__global__ __launch_bounds__(256) void k_qk2(const float* __restrict__ ctx,
                                             const float* __restrict__ Wq,
                                             const float* __restrict__ bq,
                                             const float* __restrict__ Wk,
                                             float* __restrict__ qk) {
    __shared__ float qs[CC];
    int b    = blockIdx.x >> 1;
    int half = blockIdx.x & 1;
    const float4* cr = (const float4*)(ctx + (size_t)b * DD);
    for (int c = threadIdx.x; c < CC; c += 256) {
        const float4* wr = (const float4*)(Wq + (size_t)c * DD);
        float acc = 0.f;
        #pragma unroll 8
        for (int d = 0; d < DD / 4; ++d) {
            float4 a = cr[d], w = wr[d];
            acc += a.x * w.x + a.y * w.y + a.z * w.z + a.w * w.w;
        }
        qs[c] = acc + bq[c];
    }
    __syncthreads();
    int c = half * 256 + threadIdx.x;
    float acc = 0.f;
    #pragma unroll 8
    for (int o = 0; o < CC; ++o) acc += qs[o] * Wk[(size_t)o * CC + c];
    qk[b * CC + c] = acc;
}

// ---- B: logits chunk + chunk-local softmax numerators (reads x: 268 MB) ----
// Block = (b, chunk of 256 hw). Wave w reduces channels [128w,128w+128);
// wave 0 combines, computes chunk max M / sum s, writes p = exp(l-M) + stats.
__global__ __launch_bounds__(256) void k_logits_p(const float* __restrict__ x,
                                                  const float* __restrict__ qk,
                                                  float* __restrict__ p,      // [BB][HW]
                                                  float* __restrict__ stats) {// [BB*NCHUNK][2]
    __shared__ float  qs[CC];
    __shared__ float4 comb[3][64];
    int b     = blockIdx.x >> 6;                  // NCHUNK = 64 blocks per batch
    int chunk = blockIdx.x & 63;
    int wave = threadIdx.x >> 6, lane = threadIdx.x & 63;
    int hw4 = chunk * 64 + lane;
    for (int i = threadIdx.x; i < CC; i += 256) qs[i] = qk[b * CC + i];
    __syncthreads();
    const float4* x4 = (const float4*)x;
    size_t base = (size_t)b * CC * HW4 + (size_t)(wave * 128) * HW4 + hw4;
    float ax = 0.f, ay = 0.f, az = 0.f, aw = 0.f;
    #pragma unroll 8
    for (int c = 0; c < 128; ++c) {
        float4 v = x4[base + (size_t)c * HW4];
        float w = qs[wave * 128 + c];
        ax += w * v.x; ay += w * v.y; az += w * v.z; aw += w * v.w;
    }
    if (wave > 0) {
        float4 pp = { ax, ay, az, aw };
        comb[wave - 1][lane] = pp;
    }
    __syncthreads();
    if (wave == 0) {
        #pragma unroll
        for (int w2 = 0; w2 < 3; ++w2) {
            float4 pp = comb[w2][lane];
            ax += pp.x; ay += pp.y; az += pp.z; aw += pp.w;
        }
        const float scale = 0.04419417382415922f; // 512^-0.5
        ax *= scale; ay *= scale; az *= scale; aw *= scale;
        float m = fmaxf(fmaxf(ax, ay), fmaxf(az, aw));
        #pragma unroll
        for (int off = 32; off; off >>= 1) m = fmaxf(m, __shfl_xor(m, off));
        float4 o;                                  // chunk-local numerators
        o.x = expf(ax - m); o.y = expf(ay - m);
        o.z = expf(az - m); o.w = expf(aw - m);
        float s = o.x + o.y + o.z + o.w;
        #pragma unroll
        for (int off = 32; off; off >>= 1) s += __shfl_xor(s, off);
        ((float4*)p)[(size_t)b * HW4 + hw4] = o;
        if (lane == 0) { stats[blockIdx.x * 2] = m; stats[blockIdx.x * 2 + 1] = s; }
    }
}

// ---- C: pooled[b,c] = sum_hw attn*x  (reads x: 268 MB, contiguous rows) ----
// One (b,c) row per block. Wave 0 derives wgt[ch] = e^{M_ch-M}/D from the 64
// stats pairs (L2-resident, <1 µs). wgt[i>>6] is wave-uniform -> LDS broadcast.
__global__ __launch_bounds__(256) void k_pool(const float* __restrict__ x,
                                              const float* __restrict__ p,
                                              const float* __restrict__ stats,
                                              float* __restrict__ pooled) {
    __shared__ float wgt[NCHUNK];
    int bc = blockIdx.x;                          // 0..4095, one (b,c) row each
    int b  = bc >> 9;
    int tid = threadIdx.x;
    if (tid < 64) {                               // one full wave -> shfl defined
        float mc = stats[(b * NCHUNK + tid) * 2];
        float sc = stats[(b * NCHUNK + tid) * 2 + 1];
        float m = mc;
        #pragma unroll
        for (int off = 32; off; off >>= 1) m = fmaxf(m, __shfl_xor(m, off));
        float w = expf(mc - m);
        float d = w * sc;
        #pragma unroll
        for (int off = 32; off; off >>= 1) d += __shfl_xor(d, off);
        wgt[tid] = w / d;                         // normalization folded in
    }
    __syncthreads();
    const float4* xr = (const float4*)x + (size_t)bc * HW4;
    const float4* pr = (const float4*)p + (size_t)b  * HW4;
    float acc = 0.f;
    #pragma unroll 8
    for (int i = tid; i < HW4; i += 256) {
        float4 xv = xr[i], pv = pr[i];            // p row is L2/L3-resident
        acc += wgt[i >> 6] * (xv.x * pv.x + xv.y * pv.y + xv.z * pv.z + xv.w * pv.w);
    }
    for (int off = 32; off; off >>= 1) acc += __shfl_down(acc, off);
    __shared__ float red[4];
    if ((tid & 63) == 0) red[tid >> 6] = acc;
    __syncthreads();
    if (tid == 0) pooled[bc] = red[0] + red[1] + red[2] + red[3];
}

// ---- D: gate[b,o] = Wv[o,:]·pooled[b,:] + bv[o]   (tiny) ----
__global__ __launch_bounds__(256) void k_gate(const float* __restrict__ pooled,
                                              const float* __restrict__ Wv,
                                              const float* __restrict__ bv,
                                              float* __restrict__ gate) {
    int t = blockIdx.x * 256 + threadIdx.x;       // 0..4095
    int b = t >> 9, o = t & (CC - 1);
    const float4* pr = (const float4*)(pooled + (size_t)b * CC);
    const float4* wr = (const float4*)(Wv + (size_t)o * CC);
    float acc = 0.f;
    #pragma unroll 8
    for (int i = 0; i < CC / 4; ++i) {
        float4 pv = pr[i], w = wr[i];
        acc += pv.x * w.x + pv.y * w.y + pv.z * w.z + pv.w * w.w;
    }
    gate[t] = acc + bv[o];
}

// ---- E: out[b,c,hw] = x[b,c,hw] * gate[b,c]   (read+write: 536 MB) ----
__global__ __launch_bounds__(256) void k_out(const float* __restrict__ x,
                                             const float* __restrict__ gate,
                                             float* __restrict__ out) {
    int bc = blockIdx.x;                          // 0..4095
    float g = gate[bc];
    const float4* xr = (const float4*)x   + (size_t)bc * HW4;
    float4*       orow = (float4*)out     + (size_t)bc * HW4;
    #pragma unroll 8
    for (int i = threadIdx.x; i < HW4; i += 256) {
        float4 v = xr[i];
        float4 o = { v.x * g, v.y * g, v.z * g, v.w * g };
        orow[i] = o;
    }
}

extern "C" void kernel_launch(void* const* d_in, const int* in_sizes, int n_in,
                              void* d_out, int out_size, void* d_ws, size_t ws_size,
                              hipStream_t stream) {
    const float* x   = (const float*)d_in[0];
    const float* ctx = (const float*)d_in[1];
    const float* Wq  = (const float*)d_in[2];
    const float* bq  = (const float*)d_in[3];
    const float* Wk  = (const float*)d_in[4];
    // d_in[5] = bk: per-batch constant in logits -> dropped (softmax shift-invariant)
    const float* Wv  = (const float*)d_in[6];
    const float* bv  = (const float*)d_in[7];
    float* out = (float*)d_out;

    // Workspace layout (floats): everything written before read, no zero-init.
    float* ws     = (float*)d_ws;
    float* qk     = ws;                 // 4096
    float* pooled = ws + 4096;          // 4096
    float* gate   = ws + 8192;          // 4096
    float* stats  = ws + 12288;         // 1024  (512 chunks x {M, s})
    float* p      = ws + 13312;         // 131072 (softmax numerators)

    k_qk2     <<<  16, 256, 0, stream>>>(ctx, Wq, bq, Wk, qk);
    k_logits_p<<< 512, 256, 0, stream>>>(x, qk, p, stats);
    k_pool    <<<4096, 256, 0, stream>>>(x, p, stats, pooled);
    k_gate    <<<  16, 256, 0, stream>>>(pooled, Wv, bv, gate);
    k_out     <<<4096, 256, 0, stream>>>(x, gate, out);
}